// Round 9
// baseline (149.836 us; speedup 1.0000x reference)
//
#include <hip/hip_runtime.h>

// ---------------------------------------------------------------------------
// Compile-time Cayley tables for PGA G(3,0,1), basis ordered by grade:
// idx: 0:1 1:e0 2:e1 3:e2 4:e3 5:e01 6:e02 7:e03 8:e12 9:e13 10:e23
//      11:e012 12:e013 13:e023 14:e123 15:e0123
// Blade as 4-bit mask: e0=bit0, e1=bit1, e2=bit2, e3=bit3.
// ---------------------------------------------------------------------------
namespace ga {

constexpr int MASK[16]        = {0,1,2,4,8,3,5,9,6,10,12,7,11,13,14,15};
constexpr int IDX_OF_MASK[16] = {0,1,2,5,3,6,8,11,4,7,9,12,10,13,14,15};

constexpr int popc(int v) { int c = 0; while (v) { c += v & 1; v >>= 1; } return c; }

constexpr int reorder_sign(int a, int b) {
    int s = 0; int t = a >> 1;
    while (t) { s += popc(t & b); t >>= 1; }
    return (s & 1) ? -1 : 1;
}

struct Term { signed char i, j, k, s; };

// Geometric product, metric (0,1,1,1): 192 nonzero terms.
struct GPTab { Term t[192]; };
constexpr GPTab build_gp() {
    GPTab T{}; int n = 0;
    for (int i = 0; i < 16; i++)
        for (int j = 0; j < 16; j++) {
            int a = MASK[i], b = MASK[j];
            if (a & b & 1) continue;                 // e0^2 = 0
            T.t[n].i = (signed char)i;
            T.t[n].j = (signed char)j;
            T.t[n].k = (signed char)IDX_OF_MASK[a ^ b];
            T.t[n].s = (signed char)reorder_sign(a, b);
            n++;
        }
    return T;
}

// Join (sans ref scale): dual(dual(x) ^ dual(y)) folded to 81 terms.
struct JNTab { Term t[81]; };
constexpr JNTab build_join() {
    JNTab T{}; int n = 0;
    int didx[16] = {}, dsgn[16] = {};
    for (int i = 0; i < 16; i++) {
        int a = MASK[i], c = (~a) & 0xF;
        didx[i] = IDX_OF_MASK[c];
        dsgn[i] = reorder_sign(a, c);
    }
    for (int i = 0; i < 16; i++)
        for (int j = 0; j < 16; j++) {
            int p = didx[i], q = didx[j];
            int a = MASK[p], b = MASK[q];
            if (a & b) continue;
            int m = IDX_OF_MASK[a | b];
            int k = didx[m];
            int s = dsgn[i] * dsgn[j] * dsgn[m] * reorder_sign(a, b);
            T.t[n].i = (signed char)i;
            T.t[n].j = (signed char)j;
            T.t[n].k = (signed char)k;
            T.t[n].s = (signed char)s;
            n++;
        }
    return T;
}

constexpr GPTab G = build_gp();
constexpr JNTab J = build_join();

} // namespace ga

// ---------------------------------------------------------------------------
// R9 = R8 with the nontemporal-store compile fix: __builtin_nontemporal_store
// requires a NATIVE clang vector (HIP float4 is a class). Use
// ext_vector_type(4) float — bit-identical 16-B layout.
//
// Theory under test (from R7 post-mortem): five structures all pin at
// ~3.3 TB/s logical with all pipes idle. Inputs are L3-hot (FETCH 49 MB <<
// 134 MB logical), so L3 serves ~85 MB of reads WHILE absorbing the 65.5 MB
// write-allocate stream (~200 MB/49.6us ≈ 4 TB/s at the L3). Changes:
//  (a) nt stores — write-once output bypasses L2/L3 allocation, freeing the
//      cache path for reads.
//  (b) vmcnt schedule never waits on stores mid-loop (R7's vmcnt(9) provably
//      drained ST i-1 every iteration — store-ack latency chained into the
//      load path):
//        first iter:  DMA0(9)+DMA1(9) outstanding          -> vmcnt(9)
//        middle:      DMA i(9), ST i-1(8), DMA i+1(9)      -> vmcnt(17)
//        last:        DMA n(9), ST n-1(8)                  -> vmcnt(8)
//        single-chunk block:                                  vmcnt(0)
//
// Everything else identical to R7 (LDS-DMA double-buffer, zero spills,
// 36-stride overlay, 18.9 KB LDS -> 8 single-wave blocks/CU, grid 2048).
// ---------------------------------------------------------------------------
constexpr int BUF_FLOATS = 2304;   // 9 KB per buffer
constexpr int OSTRIDE    = 36;

typedef const __attribute__((address_space(1))) void* gas_ptr;
typedef __attribute__((address_space(3))) void*       las_ptr;
typedef float nt_f4 __attribute__((ext_vector_type(4)));   // native vec for nt store

__global__ __launch_bounds__(64, 2)
void MVGeometricBilinear_kernel(const float* __restrict__ x,
                                const float* __restrict__ y,
                                const float* __restrict__ ref,
                                float* __restrict__ out,
                                int nchunks, int niter)
{
    __shared__ __align__(16) float buf[2][BUF_FLOATS];
    __shared__ __align__(16) float rbuf[2][64];

    const int lane = threadIdx.x;          // block == 1 wave
    long chunk = (long)blockIdx.x * niter;
    long cend  = chunk + niter;
    if (cend > nchunks) cend = nchunks;
    if (chunk >= cend) return;

    // 9 DMA ops: x -> buf[b][0..1023], y -> buf[b][1024..2047], ref -> rbuf[b].
    auto dma_chunk = [&](long c, int b) {
        const float4* gx = reinterpret_cast<const float4*>(x) + c * 256;
        const float4* gy = reinterpret_cast<const float4*>(y) + c * 256;
#pragma unroll
        for (int k = 0; k < 4; k++) {
            __builtin_amdgcn_global_load_lds((gas_ptr)(gx + k * 64 + lane),
                                             (las_ptr)(&buf[b][k * 256]), 16, 0, 0);
            __builtin_amdgcn_global_load_lds((gas_ptr)(gy + k * 64 + lane),
                                             (las_ptr)(&buf[b][1024 + k * 256]), 16, 0, 0);
        }
        __builtin_amdgcn_global_load_lds((gas_ptr)(ref + (c * 64 + lane) * 16 + 15),
                                         (las_ptr)(&rbuf[b][0]), 4, 0, 0);
    };

    int cur = 0;
    int iter = 0;
    dma_chunk(chunk, 0);                   // prologue: chunk 0 -> buffer A

    while (true) {
        const long next = chunk + 1;
        const bool pf = (next < cend);     // wave-uniform

        if (pf) {
            dma_chunk(next, cur ^ 1);      // i+1 in flight across compute of i
            if (iter == 0) {
                asm volatile("s_waitcnt vmcnt(9)" ::: "memory");   // drain DMA0
            } else {
                asm volatile("s_waitcnt vmcnt(17)" ::: "memory");  // drain DMA i only
            }
        } else {
            if (iter == 0) {
                asm volatile("s_waitcnt vmcnt(0)" ::: "memory");
            } else {
                asm volatile("s_waitcnt vmcnt(8)" ::: "memory");   // drain DMA last
            }
        }

        // ---- fragments: b128 LDS reads, point-major 64 B stride ----
        const float* bx = &buf[cur][0];
        const float* by = &buf[cur][1024];
        float xx[16], yy[16];
#pragma unroll
        for (int k = 0; k < 4; k++) {
            const float4 vx = *reinterpret_cast<const float4*>(bx + lane * 16 + k * 4);
            const float4 vy = *reinterpret_cast<const float4*>(by + lane * 16 + k * 4);
            xx[4*k+0] = vx.x; xx[4*k+1] = vx.y; xx[4*k+2] = vx.z; xx[4*k+3] = vx.w;
            yy[4*k+0] = vy.x; yy[4*k+1] = vy.y; yy[4*k+2] = vy.z; yy[4*k+3] = vy.w;
        }
        const float r = rbuf[cur][lane];

        // ---- compute ----
        float gp[16] = {0.f, 0.f, 0.f, 0.f, 0.f, 0.f, 0.f, 0.f,
                        0.f, 0.f, 0.f, 0.f, 0.f, 0.f, 0.f, 0.f};
        float jn[16] = {0.f, 0.f, 0.f, 0.f, 0.f, 0.f, 0.f, 0.f,
                        0.f, 0.f, 0.f, 0.f, 0.f, 0.f, 0.f, 0.f};
#pragma unroll
        for (int t = 0; t < 192; t++) {
            const int ti = ga::G.t[t].i, tj = ga::G.t[t].j, tk = ga::G.t[t].k;
            const float v = xx[ti] * yy[tj];
            if (ga::G.t[t].s > 0) gp[tk] += v; else gp[tk] -= v;
        }
#pragma unroll
        for (int t = 0; t < 81; t++) {
            const int ti = ga::J.t[t].i, tj = ga::J.t[t].j, tk = ga::J.t[t].k;
            const float v = xx[ti] * yy[tj];
            if (ga::J.t[t].s > 0) jn[tk] += v; else jn[tk] -= v;
        }

        // Fence: frag reads stay above, lo-overlay writes stay below
        // (cross-lane WAR invisible to per-thread alias analysis — R3 lesson).
        asm volatile("" ::: "memory");

        // ---- stage results: 36-stride overlay over current buffer ----
        float* lo = &buf[cur][0];
#pragma unroll
        for (int k = 0; k < 4; k++)
            *reinterpret_cast<float4*>(lo + lane * OSTRIDE + k * 4) =
                make_float4(gp[4*k+0], gp[4*k+1], gp[4*k+2], gp[4*k+3]);
#pragma unroll
        for (int k = 0; k < 4; k++)
            *reinterpret_cast<float4*>(lo + lane * OSTRIDE + 16 + k * 4) =
                make_float4(r * jn[4*k+0], r * jn[4*k+1], r * jn[4*k+2], r * jn[4*k+3]);

        // ---- cooperative unit-stride NONTEMPORAL store: 512 float4/chunk ----
        // nt bypasses L2/L3 allocation — write-once stream stays out of the
        // cache path that serves the read stream.
        nt_f4* go = reinterpret_cast<nt_f4*>(out) + chunk * 512;
#pragma unroll
        for (int c = 0; c < 8; c++) {
            const int g  = lane + 64 * c;
            const int p  = g >> 3;
            const int ch = g & 7;
            const nt_f4 v = *reinterpret_cast<const nt_f4*>(lo + p * OSTRIDE + ch * 4);
            __builtin_nontemporal_store(v, go + g);
        }

        // Fence: lo reads stay above anything the next iteration does.
        asm volatile("" ::: "memory");

        if (!pf) break;
        cur ^= 1;
        chunk = next;
        iter++;
    }
}

// Tail path (npts not divisible by 64) — scalar per-thread, same math.
__global__ __launch_bounds__(64)
void MVGeometricBilinear_tail(const float* __restrict__ x,
                              const float* __restrict__ y,
                              const float* __restrict__ ref,
                              float* __restrict__ out,
                              int start, int npts)
{
    int pt = start + blockIdx.x * 64 + threadIdx.x;
    if (pt >= npts) return;
    float xx[16], yy[16];
#pragma unroll
    for (int k = 0; k < 16; k++) { xx[k] = x[(size_t)pt*16+k]; yy[k] = y[(size_t)pt*16+k]; }
    const float r = ref[(size_t)pt*16+15];
    float gp[16] = {}, jn[16] = {};
#pragma unroll
    for (int t = 0; t < 192; t++) {
        const float v = xx[ga::G.t[t].i] * yy[ga::G.t[t].j];
        if (ga::G.t[t].s > 0) gp[ga::G.t[t].k] += v; else gp[ga::G.t[t].k] -= v;
    }
#pragma unroll
    for (int t = 0; t < 81; t++) {
        const float v = xx[ga::J.t[t].i] * yy[ga::J.t[t].j];
        if (ga::J.t[t].s > 0) jn[ga::J.t[t].k] += v; else jn[ga::J.t[t].k] -= v;
    }
#pragma unroll
    for (int k = 0; k < 16; k++) out[(size_t)pt*32+k] = gp[k];
#pragma unroll
    for (int k = 0; k < 16; k++) out[(size_t)pt*32+16+k] = r * jn[k];
}

extern "C" void kernel_launch(void* const* d_in, const int* in_sizes, int n_in,
                              void* d_out, int out_size, void* d_ws, size_t ws_size,
                              hipStream_t stream) {
    const float* x   = (const float*)d_in[0];
    const float* y   = (const float*)d_in[1];
    const float* ref = (const float*)d_in[2];
    float* out = (float*)d_out;

    const int npts    = in_sizes[0] / 16;     // B*T = 524288
    const int nchunks = npts / 64;            // 8192
    const int niter   = 4;                    // chunks per wave
    const int blocks  = (nchunks + niter - 1) / niter;   // 2048 = 8 blocks/CU

    if (nchunks > 0) {
        MVGeometricBilinear_kernel<<<blocks, 64, 0, stream>>>(
            x, y, ref, out, nchunks, niter);
    }

    const int rem = npts - nchunks * 64;      // 0 for this shape
    if (rem > 0) {
        MVGeometricBilinear_tail<<<(rem + 63) / 64, 64, 0, stream>>>(
            x, y, ref, out, nchunks * 64, npts);
    }
}